// Round 1
// baseline (43868.860 us; speedup 1.0000x reference)
//
#include <hip/hip_runtime.h>
#include <math.h>

// Problem constants (from reference):
//   B=256, T=512, D=64, H=512, FC=512, OUT=8
#define HH   512
#define BB   256
#define TLEN 512
#define DD   64

__device__ __forceinline__ float sigm(float x) { return 1.0f / (1.0f + __expf(-x)); }

// Fused GEMM + epilogue kernel.
// Computes gates[m][n] = sum_k A1[m][k]*W1[n][k] (K1) + sum_k A2[m][k]*W2[n][k] (K2) + bias
// MODE 0: LSTM step. Block tile = 16 rows x 32 h-units; each h-unit's 4 gates
//         (rows j, H+j, 2H+j, 3H+j of W) computed in the SAME thread so the
//         c/h update is done in the epilogue (no second kernel).
// MODE 1: plain GEMM tile 16 x 128 with ReLU epilogue (fc1).
template <int MODE>
__global__ __launch_bounds__(256) void gemm_step(
    const float* __restrict__ A1, int lda1, int K1, const float* __restrict__ W1,
    const float* __restrict__ A2, int K2, const float* __restrict__ W2,
    const float* __restrict__ b1, const float* __restrict__ b2,
    const float* __restrict__ c_in, float* __restrict__ c_out,
    float* __restrict__ h_out)
{
    __shared__ float sA[16][33];    // 16 batch rows x 32 k (+1 pad)
    __shared__ float sW[128][33];   // 128 weight rows x 32 k (+1 pad)

    const int tid = threadIdx.x;
    const int tj  = tid & 31;   // 0..31  (h-unit / n within tile)
    const int tg  = tid >> 5;   // 0..7   (m group; thread owns rows tg and tg+8)
    const int m0  = blockIdx.x * 16;
    const int j0  = blockIdx.y * ((MODE == 0) ? 32 : 128);

    float acc[2][4] = {{0.f, 0.f, 0.f, 0.f}, {0.f, 0.f, 0.f, 0.f}};

    for (int seg = 0; seg < 2; ++seg) {
        const float* A  = seg ? A2 : A1;
        const float* W  = seg ? W2 : W1;
        const int    K  = seg ? K2 : K1;
        const int    ld = seg ? HH : lda1;
        if (K == 0) continue;
        for (int kb = 0; kb < K; kb += 32) {
            __syncthreads();
            // Stage A tile: 16x32 = 512 words, 2 per thread (coalesced rows)
            {
                int idx = tid;
#pragma unroll
                for (int r = 0; r < 2; ++r, idx += 256) {
                    int row = idx >> 5, col = idx & 31;
                    sA[row][col] = A[(m0 + row) * ld + kb + col];
                }
            }
            // Stage W tile: 128x32 = 4096 words, 16 per thread
            {
#pragma unroll
                for (int i = 0; i < 16; ++i) {
                    int idx = i * 256 + tid;
                    int row = idx >> 5, col = idx & 31;
                    int grow;
                    if (MODE == 0) grow = (row >> 5) * HH + j0 + (row & 31); // gate-grouped
                    else           grow = j0 + row;
                    sW[row][col] = W[grow * K + kb + col];
                }
            }
            __syncthreads();
#pragma unroll
            for (int k = 0; k < 32; ++k) {
                float a0 = sA[tg][k];
                float a1 = sA[tg + 8][k];
                float w0 = sW[tj][k];
                float w1 = sW[32 + tj][k];
                float w2 = sW[64 + tj][k];
                float w3 = sW[96 + tj][k];
                acc[0][0] += a0 * w0; acc[0][1] += a0 * w1;
                acc[0][2] += a0 * w2; acc[0][3] += a0 * w3;
                acc[1][0] += a1 * w0; acc[1][1] += a1 * w1;
                acc[1][2] += a1 * w2; acc[1][3] += a1 * w3;
            }
        }
    }

    if (MODE == 0) {
        const int j = j0 + tj;
        const float bi = b1[j] + b2[j];
        const float bf = b1[HH + j] + b2[HH + j];
        const float bg = b1[2 * HH + j] + b2[2 * HH + j];
        const float bo = b1[3 * HH + j] + b2[3 * HH + j];
#pragma unroll
        for (int r = 0; r < 2; ++r) {
            int m = m0 + tg + r * 8;
            float gi = acc[r][0] + bi;
            float gf = acc[r][1] + bf;
            float gg = acc[r][2] + bg;
            float go = acc[r][3] + bo;
            float cp = c_in[m * HH + j];
            float c  = sigm(gf) * cp + sigm(gi) * tanhf(gg);
            float h  = sigm(go) * tanhf(c);
            c_out[m * HH + j] = c;
            h_out[m * HH + j] = h;
        }
    } else {
#pragma unroll
        for (int r = 0; r < 2; ++r) {
            int m = m0 + tg + r * 8;
#pragma unroll
            for (int q = 0; q < 4; ++q) {
                int n = j0 + q * 32 + tj;
                float v = acc[r][q] + b1[n];
                h_out[m * HH + n] = fmaxf(v, 0.f);
            }
        }
    }
}

// out[m][o] = z[m][:] . W[o][:] + b[o]    (M=256, O=8, K=512)
__global__ __launch_bounds__(64) void fc2_kernel(
    const float* __restrict__ z, const float* __restrict__ W,
    const float* __restrict__ b, float* __restrict__ out)
{
    int m = blockIdx.x;
    int lane = threadIdx.x;
    float zr[8];
#pragma unroll
    for (int u = 0; u < 8; ++u) zr[u] = z[m * 512 + u * 64 + lane];
#pragma unroll
    for (int o = 0; o < 8; ++o) {
        float s = 0.f;
#pragma unroll
        for (int u = 0; u < 8; ++u) s += zr[u] * W[o * 512 + u * 64 + lane];
#pragma unroll
        for (int off = 32; off > 0; off >>= 1) s += __shfl_down(s, off);
        if (lane == 0) out[m * 8 + o] = s + b[o];
    }
}

__global__ __launch_bounds__(256) void zero_kernel(float* p, int n)
{
    int i = blockIdx.x * 256 + threadIdx.x;
    if (i < n) p[i] = 0.f;
}

extern "C" void kernel_launch(void* const* d_in, const int* in_sizes, int n_in,
                              void* d_out, int out_size, void* d_ws, size_t ws_size,
                              hipStream_t stream)
{
    const float* x     = (const float*)d_in[0];
    const float* W_ih0 = (const float*)d_in[1];
    const float* W_hh0 = (const float*)d_in[2];
    const float* b_ih0 = (const float*)d_in[3];
    const float* b_hh0 = (const float*)d_in[4];
    const float* W_ih1 = (const float*)d_in[5];
    const float* W_hh1 = (const float*)d_in[6];
    const float* b_ih1 = (const float*)d_in[7];
    const float* b_hh1 = (const float*)d_in[8];
    const float* W_fc1 = (const float*)d_in[9];
    const float* b_fc1 = (const float*)d_in[10];
    const float* W_fc2 = (const float*)d_in[11];
    const float* b_fc2 = (const float*)d_in[12];
    float* out = (float*)d_out;

    const int S = BB * HH; // 131072 floats per state buffer
    float* wsf = (float*)d_ws;
    // Layout: the 4 buffers needing zero-init come first (one memset kernel).
    float* h0a = wsf + 0 * S;  // read at t=0  -> zero
    float* c0  = wsf + 1 * S;  // zero
    float* h1a = wsf + 2 * S;  // zero
    float* c1  = wsf + 3 * S;  // zero
    float* h0b = wsf + 4 * S;  // fully written at t=0 before first read
    float* h1b = wsf + 5 * S;
    float* zb  = wsf + 6 * S;  // fc1 output

    float* h0buf[2] = {h0a, h0b};
    float* h1buf[2] = {h1a, h1b};

    zero_kernel<<<(4 * S + 255) / 256, 256, 0, stream>>>(wsf, 4 * S);

    dim3 grid_lstm(BB / 16, HH / 32); // (16,16) = 256 blocks
    for (int t = 0; t < TLEN; ++t) {
        const float* xt = x + (size_t)t * DD; // row stride T*D
        // Layer 0: gates = x_t @ W_ih0^T + h0 @ W_hh0^T + b
        gemm_step<0><<<grid_lstm, 256, 0, stream>>>(
            xt, TLEN * DD, DD, W_ih0,
            h0buf[t & 1], HH, W_hh0,
            b_ih0, b_hh0, c0, c0, h0buf[(t + 1) & 1]);
        // Layer 1: gates = h0_t @ W_ih1^T + h1 @ W_hh1^T + b
        gemm_step<0><<<grid_lstm, 256, 0, stream>>>(
            h0buf[(t + 1) & 1], HH, HH, W_ih1,
            h1buf[t & 1], HH, W_hh1,
            b_ih1, b_hh1, c1, c1, h1buf[(t + 1) & 1]);
    }
    // final h1 lives in h1buf[(511+1)&1] = h1buf[0]
    dim3 grid_fc1(BB / 16, 512 / 128); // (16,4)
    gemm_step<1><<<grid_fc1, 256, 0, stream>>>(
        h1buf[0], HH, HH, W_fc1,
        nullptr, 0, nullptr,
        b_fc1, nullptr, nullptr, nullptr, zb);
    fc2_kernel<<<BB, 64, 0, stream>>>(zb, W_fc2, b_fc2, out);
}

// Round 2
// 11426.918 us; speedup vs baseline: 3.8391x; 3.8391x over previous
//
#include <hip/hip_runtime.h>
#include <math.h>

typedef unsigned short u16;
typedef __attribute__((ext_vector_type(8))) short short8;
typedef __attribute__((ext_vector_type(4))) float float4v;

#define HH   512
#define BB   256
#define TLEN 512
#define DD   64

__device__ __forceinline__ float sigm(float x) { return 1.0f / (1.0f + __expf(-x)); }

__device__ __forceinline__ u16 bf16rn(float v) {
    unsigned u = __float_as_uint(v);
    u += 0x7fffu + ((u >> 16) & 1u);
    return (u16)(u >> 16);
}
__device__ __forceinline__ float bf16tf(u16 h) { return __uint_as_float(((unsigned)h) << 16); }

// ---------------- precompute kernels ----------------

__global__ __launch_bounds__(256) void split_kernel(const float* __restrict__ src,
                                                    u16* __restrict__ hi, u16* __restrict__ lo, int n)
{
    for (int i = blockIdx.x * 256 + threadIdx.x; i < n; i += gridDim.x * 256) {
        float v = src[i];
        u16 h = bf16rn(v);
        hi[i] = h;
        lo[i] = bf16rn(v - bf16tf(h));
    }
}

__global__ __launch_bounds__(256) void zero_kernel(unsigned* p, int n)
{
    int i = blockIdx.x * 256 + threadIdx.x;
    if (i < n) p[i] = 0u;
}

// ---------------- fused LSTM step (both layers, pipelined) ----------------
// Launch n: blocks 0..127  -> layer0 step t=n     (skip if n==512)
//           blocks 128..255-> layer1 step t=n-1   (skip if n==0)
// Block tile: m64 x 16 h-units (64 gate cols). 4 waves; wave w = m-subtile w (16 rows)
// x all 4 gate n-tiles. acc_g[r]: D[m=(lane>>4)*4+r][j=lane&15] for gate g.
__global__ __launch_bounds__(256) void lstm_step(
    int n,
    const u16* __restrict__ xhi, const u16* __restrict__ xlo,
    const u16* __restrict__ Wih0h, const u16* __restrict__ Wih0l,
    const u16* __restrict__ Whh0h, const u16* __restrict__ Whh0l,
    const u16* __restrict__ Wih1h, const u16* __restrict__ Wih1l,
    const u16* __restrict__ Whh1h, const u16* __restrict__ Whh1l,
    const float* __restrict__ bi0, const float* __restrict__ bh0,
    const float* __restrict__ bi1, const float* __restrict__ bh1,
    const u16* __restrict__ h0rh, const u16* __restrict__ h0rl,
    u16* __restrict__ h0wh, u16* __restrict__ h0wl,
    const u16* __restrict__ h1rh, const u16* __restrict__ h1rl,
    u16* __restrict__ h1wh, u16* __restrict__ h1wl,
    float* __restrict__ c0, float* __restrict__ c1,
    float* __restrict__ h1last)
{
    __shared__ u16 sBh[2][2048]; // [buf][64 gate-rows x 32 k]
    __shared__ u16 sBl[2][2048];

    const int tid  = threadIdx.x;
    const int lane = tid & 63;
    const int wv   = tid >> 6;
    const bool role1 = (blockIdx.x >= 128);
    const int idx = blockIdx.x & 127;
    const int m0  = (idx & 3) * 64;
    const int j0  = (idx >> 2) * 16;

    if (!role1 && n == TLEN) return;
    if (role1 && n == 0) return;

    const u16 *A1h, *A1l, *A2h, *A2l, *B1h, *B1l, *B2h, *B2l;
    int ld1, C1, C, ldb1;
    if (!role1) {
        A1h = xhi + (size_t)n * DD; A1l = xlo + (size_t)n * DD; ld1 = TLEN * DD; C1 = 2;
        A2h = h0rh; A2l = h0rl;
        B1h = Wih0h; B1l = Wih0l; ldb1 = DD;
        B2h = Whh0h; B2l = Whh0l;
        C = 18;                      // 64/32 + 512/32
    } else {
        A1h = h0rh; A1l = h0rl; ld1 = HH; C1 = 16;
        A2h = h1rh; A2l = h1rl;
        B1h = Wih1h; B1l = Wih1l; ldb1 = HH;
        B2h = Whh1h; B2l = Whh1l;
        C = 32;                      // 512/32 + 512/32
    }

    // B staging: thread -> gate-row r=tid>>2 (g=r>>4, j=r&15), ksub=(tid&3)*8
    const int br   = tid >> 2;
    const int grow = (br >> 4) * HH + j0 + (br & 15);
    const int bks  = (tid & 3) * 8;
    // A fragment: row = m0 + wv*16 + (lane&15), k-offset (lane>>4)*8
    const int arow = m0 + wv * 16 + (lane & 15);
    const int akq  = (lane >> 4) * 8;

    auto bptr = [&](int c, const u16* P1, const u16* P2) -> const u16* {
        return (c < C1) ? (P1 + (size_t)grow * ldb1 + c * 32 + bks)
                        : (P2 + (size_t)grow * HH + (size_t)(c - C1) * 32 + bks);
    };
    auto aptr = [&](int c, const u16* P1, const u16* P2) -> const u16* {
        return (c < C1) ? (P1 + (size_t)arow * ld1 + c * 32 + akq)
                        : (P2 + (size_t)arow * HH + (size_t)(c - C1) * 32 + akq);
    };

    float4v zf = {0.f, 0.f, 0.f, 0.f};
    float4v acc0 = zf, acc1 = zf, acc2 = zf, acc3 = zf;

    // prologue: stage chunk 0, prefetch A frags for chunk 0
    short8 svh = *(const short8*)bptr(0, B1h, B2h);
    short8 svl = *(const short8*)bptr(0, B1l, B2l);
    short8 ah  = *(const short8*)aptr(0, A1h, A2h);
    short8 al  = *(const short8*)aptr(0, A1l, A2l);
    *(short8*)&sBh[0][tid * 8] = svh;
    *(short8*)&sBl[0][tid * 8] = svl;

    const int fo = (lane & 15) * 32 + akq; // frag offset within a 16-row gate tile

    for (int c = 0; c < C; ++c) {
        __syncthreads();                   // buf[c&1] staged & visible; prev reads done
        short8 nvh, nvl, nah, nal;
        const bool more = (c + 1 < C);
        if (more) {                        // issue next-chunk loads (overlap with MFMA)
            nvh = *(const short8*)bptr(c + 1, B1h, B2h);
            nvl = *(const short8*)bptr(c + 1, B1l, B2l);
            nah = *(const short8*)aptr(c + 1, A1h, A2h);
            nal = *(const short8*)aptr(c + 1, A1l, A2l);
        }
        const int buf = c & 1;
        short8 b0h = *(const short8*)&sBh[buf][0 * 512 + fo];
        short8 b1h = *(const short8*)&sBh[buf][1 * 512 + fo];
        short8 b2h = *(const short8*)&sBh[buf][2 * 512 + fo];
        short8 b3h = *(const short8*)&sBh[buf][3 * 512 + fo];
        short8 b0l = *(const short8*)&sBl[buf][0 * 512 + fo];
        short8 b1l = *(const short8*)&sBl[buf][1 * 512 + fo];
        short8 b2l = *(const short8*)&sBl[buf][2 * 512 + fo];
        short8 b3l = *(const short8*)&sBl[buf][3 * 512 + fo];

        acc0 = __builtin_amdgcn_mfma_f32_16x16x32_bf16(ah, b0h, acc0, 0, 0, 0);
        acc1 = __builtin_amdgcn_mfma_f32_16x16x32_bf16(ah, b1h, acc1, 0, 0, 0);
        acc2 = __builtin_amdgcn_mfma_f32_16x16x32_bf16(ah, b2h, acc2, 0, 0, 0);
        acc3 = __builtin_amdgcn_mfma_f32_16x16x32_bf16(ah, b3h, acc3, 0, 0, 0);
        acc0 = __builtin_amdgcn_mfma_f32_16x16x32_bf16(ah, b0l, acc0, 0, 0, 0);
        acc1 = __builtin_amdgcn_mfma_f32_16x16x32_bf16(ah, b1l, acc1, 0, 0, 0);
        acc2 = __builtin_amdgcn_mfma_f32_16x16x32_bf16(ah, b2l, acc2, 0, 0, 0);
        acc3 = __builtin_amdgcn_mfma_f32_16x16x32_bf16(ah, b3l, acc3, 0, 0, 0);
        acc0 = __builtin_amdgcn_mfma_f32_16x16x32_bf16(al, b0h, acc0, 0, 0, 0);
        acc1 = __builtin_amdgcn_mfma_f32_16x16x32_bf16(al, b1h, acc1, 0, 0, 0);
        acc2 = __builtin_amdgcn_mfma_f32_16x16x32_bf16(al, b2h, acc2, 0, 0, 0);
        acc3 = __builtin_amdgcn_mfma_f32_16x16x32_bf16(al, b3h, acc3, 0, 0, 0);

        if (more) {
            *(short8*)&sBh[buf ^ 1][tid * 8] = nvh;  // waits vmcnt for staged loads
            *(short8*)&sBl[buf ^ 1][tid * 8] = nvl;
            ah = nah; al = nal;
        }
    }

    // epilogue: all 4 gates of (m, j) live in this lane
    const float* pbi = role1 ? bi1 : bi0;
    const float* pbh = role1 ? bh1 : bh0;
    float* cc = role1 ? c1 : c0;
    u16* wh = role1 ? h1wh : h0wh;
    u16* wl = role1 ? h1wl : h0wl;
    const int jj = j0 + (lane & 15);
    const float bI = pbi[jj] + pbh[jj];
    const float bF = pbi[HH + jj] + pbh[HH + jj];
    const float bG = pbi[2 * HH + jj] + pbh[2 * HH + jj];
    const float bO = pbi[3 * HH + jj] + pbh[3 * HH + jj];
    const int mbase = m0 + wv * 16 + (lane >> 4) * 4;
#pragma unroll
    for (int r = 0; r < 4; ++r) {
        const size_t off = (size_t)(mbase + r) * HH + jj;
        float gi = acc0[r] + bI;
        float gf = acc1[r] + bF;
        float gg = acc2[r] + bG;
        float go = acc3[r] + bO;
        float cp = cc[off];
        float cn = sigm(gf) * cp + sigm(gi) * tanhf(gg);
        float h  = sigm(go) * tanhf(cn);
        cc[off] = cn;
        u16 hv = bf16rn(h);
        wh[off] = hv;
        wl[off] = bf16rn(h - bf16tf(hv));
        if (role1) h1last[off] = h;
    }
}

// ---------------- FC head (fp32, proven in round 1) ----------------

template <int MODE>
__global__ __launch_bounds__(256) void gemm_step(
    const float* __restrict__ A1, int lda1, int K1, const float* __restrict__ W1,
    const float* __restrict__ A2, int K2, const float* __restrict__ W2,
    const float* __restrict__ b1, const float* __restrict__ b2,
    const float* __restrict__ c_in, float* __restrict__ c_out,
    float* __restrict__ h_out)
{
    __shared__ float sA[16][33];
    __shared__ float sW[128][33];

    const int tid = threadIdx.x;
    const int tj  = tid & 31;
    const int tg  = tid >> 5;
    const int m0  = blockIdx.x * 16;
    const int j0  = blockIdx.y * ((MODE == 0) ? 32 : 128);

    float acc[2][4] = {{0.f, 0.f, 0.f, 0.f}, {0.f, 0.f, 0.f, 0.f}};

    for (int seg = 0; seg < 2; ++seg) {
        const float* A  = seg ? A2 : A1;
        const float* W  = seg ? W2 : W1;
        const int    K  = seg ? K2 : K1;
        const int    ld = seg ? HH : lda1;
        if (K == 0) continue;
        for (int kb = 0; kb < K; kb += 32) {
            __syncthreads();
            {
                int idxq = tid;
#pragma unroll
                for (int r = 0; r < 2; ++r, idxq += 256) {
                    int row = idxq >> 5, col = idxq & 31;
                    sA[row][col] = A[(m0 + row) * ld + kb + col];
                }
            }
            {
#pragma unroll
                for (int i = 0; i < 16; ++i) {
                    int idxq = i * 256 + tid;
                    int row = idxq >> 5, col = idxq & 31;
                    int grw;
                    if (MODE == 0) grw = (row >> 5) * HH + j0 + (row & 31);
                    else           grw = j0 + row;
                    sW[row][col] = W[grw * K + kb + col];
                }
            }
            __syncthreads();
#pragma unroll
            for (int k = 0; k < 32; ++k) {
                float a0 = sA[tg][k];
                float a1 = sA[tg + 8][k];
                float w0 = sW[tj][k];
                float w1 = sW[32 + tj][k];
                float w2 = sW[64 + tj][k];
                float w3 = sW[96 + tj][k];
                acc[0][0] += a0 * w0; acc[0][1] += a0 * w1;
                acc[0][2] += a0 * w2; acc[0][3] += a0 * w3;
                acc[1][0] += a1 * w0; acc[1][1] += a1 * w1;
                acc[1][2] += a1 * w2; acc[1][3] += a1 * w3;
            }
        }
    }

    if (MODE == 0) {
        const int j = j0 + tj;
        const float bi = b1[j] + b2[j];
        const float bf = b1[HH + j] + b2[HH + j];
        const float bg = b1[2 * HH + j] + b2[2 * HH + j];
        const float bo = b1[3 * HH + j] + b2[3 * HH + j];
#pragma unroll
        for (int r = 0; r < 2; ++r) {
            int m = m0 + tg + r * 8;
            float gi = acc[r][0] + bi;
            float gf = acc[r][1] + bf;
            float gg = acc[r][2] + bg;
            float go = acc[r][3] + bo;
            float cp = c_in[m * HH + j];
            float c  = sigm(gf) * cp + sigm(gi) * tanhf(gg);
            float h  = sigm(go) * tanhf(c);
            c_out[m * HH + j] = c;
            h_out[m * HH + j] = h;
        }
    } else {
#pragma unroll
        for (int r = 0; r < 2; ++r) {
            int m = m0 + tg + r * 8;
#pragma unroll
            for (int q = 0; q < 4; ++q) {
                int nn = j0 + q * 32 + tj;
                float v = acc[r][q] + b1[nn];
                h_out[m * HH + nn] = fmaxf(v, 0.f);
            }
        }
    }
}

__global__ __launch_bounds__(64) void fc2_kernel(
    const float* __restrict__ z, const float* __restrict__ W,
    const float* __restrict__ b, float* __restrict__ out)
{
    int m = blockIdx.x;
    int lane = threadIdx.x;
    float zr[8];
#pragma unroll
    for (int u = 0; u < 8; ++u) zr[u] = z[m * 512 + u * 64 + lane];
#pragma unroll
    for (int o = 0; o < 8; ++o) {
        float s = 0.f;
#pragma unroll
        for (int u = 0; u < 8; ++u) s += zr[u] * W[o * 512 + u * 64 + lane];
#pragma unroll
        for (int off = 32; off > 0; off >>= 1) s += __shfl_down(s, off);
        if (lane == 0) out[m * 8 + o] = s + b[o];
    }
}

__global__ __launch_bounds__(256) void zero_f_kernel(float* p, int n)
{
    int i = blockIdx.x * 256 + threadIdx.x;
    if (i < n) p[i] = 0.f;
}

// ---------------- host ----------------

extern "C" void kernel_launch(void* const* d_in, const int* in_sizes, int n_in,
                              void* d_out, int out_size, void* d_ws, size_t ws_size,
                              hipStream_t stream)
{
    const float* x     = (const float*)d_in[0];
    const float* W_ih0 = (const float*)d_in[1];
    const float* W_hh0 = (const float*)d_in[2];
    const float* b_ih0 = (const float*)d_in[3];
    const float* b_hh0 = (const float*)d_in[4];
    const float* W_ih1 = (const float*)d_in[5];
    const float* W_hh1 = (const float*)d_in[6];
    const float* b_ih1 = (const float*)d_in[7];
    const float* b_hh1 = (const float*)d_in[8];
    const float* W_fc1 = (const float*)d_in[9];
    const float* b_fc1 = (const float*)d_in[10];
    const float* W_fc2 = (const float*)d_in[11];
    const float* b_fc2 = (const float*)d_in[12];
    float* out = (float*)d_out;

    const size_t S  = (size_t)BB * HH;        // 131072 elems
    const size_t SB = S * sizeof(u16);        // 262144 B
    const size_t SF = S * sizeof(float);      // 524288 B

    const size_t NEED = 2097152 /*zero region*/ + 4 * SB /*other h bufs*/ +
                        2 * SF /*h1last,zfc*/ + 2 * (size_t)BB * TLEN * DD * 2 /*x split*/ +
                        2 * 131072 * 2 /*Wih0*/ + 3 * 2 * 1048576 * 2 /*Whh0,Wih1,Whh1*/;

    if (ws_size >= NEED) {
        char* W = (char*)d_ws;
        size_t o = 0;
        u16 *h0hi[2], *h0lo[2], *h1hi[2], *h1lo[2];
        // zero region first (2 MB)
        h0hi[0] = (u16*)(W + o); o += SB;
        h0lo[0] = (u16*)(W + o); o += SB;
        h1hi[1] = (u16*)(W + o); o += SB;
        h1lo[1] = (u16*)(W + o); o += SB;
        float* c0 = (float*)(W + o); o += SF;
        float* c1 = (float*)(W + o); o += SF;
        // rest
        h0hi[1] = (u16*)(W + o); o += SB;
        h0lo[1] = (u16*)(W + o); o += SB;
        h1hi[0] = (u16*)(W + o); o += SB;
        h1lo[0] = (u16*)(W + o); o += SB;
        float* h1last = (float*)(W + o); o += SF;
        float* zfc    = (float*)(W + o); o += SF;
        const size_t XN = (size_t)BB * TLEN * DD; // 8388608
        u16* xhi = (u16*)(W + o); o += XN * 2;
        u16* xlo = (u16*)(W + o); o += XN * 2;
        u16* wih0h = (u16*)(W + o); o += 131072 * 2;
        u16* wih0l = (u16*)(W + o); o += 131072 * 2;
        u16* whh0h = (u16*)(W + o); o += 1048576 * 2;
        u16* whh0l = (u16*)(W + o); o += 1048576 * 2;
        u16* wih1h = (u16*)(W + o); o += 1048576 * 2;
        u16* wih1l = (u16*)(W + o); o += 1048576 * 2;
        u16* whh1h = (u16*)(W + o); o += 1048576 * 2;
        u16* whh1l = (u16*)(W + o); o += 1048576 * 2;

        // zero-init: 2 MB = 524288 u32
        zero_kernel<<<2048, 256, 0, stream>>>((unsigned*)d_ws, 524288);
        // splits
        split_kernel<<<2048, 256, 0, stream>>>(x, xhi, xlo, (int)XN);
        split_kernel<<<512, 256, 0, stream>>>(W_ih0, wih0h, wih0l, 131072);
        split_kernel<<<2048, 256, 0, stream>>>(W_hh0, whh0h, whh0l, 1048576);
        split_kernel<<<2048, 256, 0, stream>>>(W_ih1, wih1h, wih1l, 1048576);
        split_kernel<<<2048, 256, 0, stream>>>(W_hh1, whh1h, whh1l, 1048576);

        for (int n = 0; n <= TLEN; ++n) {
            int rb = n & 1, wb = (n + 1) & 1;
            lstm_step<<<256, 256, 0, stream>>>(
                n, xhi, xlo,
                wih0h, wih0l, whh0h, whh0l,
                wih1h, wih1l, whh1h, whh1l,
                b_ih0, b_hh0, b_ih1, b_hh1,
                h0hi[rb], h0lo[rb], h0hi[wb], h0lo[wb],
                h1hi[rb], h1lo[rb], h1hi[wb], h1lo[wb],
                c0, c1, h1last);
        }

        dim3 grid_fc1(BB / 16, 512 / 128);
        gemm_step<1><<<grid_fc1, 256, 0, stream>>>(
            h1last, HH, HH, W_fc1, nullptr, 0, nullptr,
            b_fc1, nullptr, nullptr, nullptr, zfc);
        fc2_kernel<<<BB, 64, 0, stream>>>(zfc, W_fc2, b_fc2, out);
        return;
    }

    // -------- fallback: round-1 fp32 path (needs ~3.7 MB ws) --------
    float* wsf = (float*)d_ws;
    float* h0a = wsf + 0 * S;
    float* c0  = wsf + 1 * S;
    float* h1a = wsf + 2 * S;
    float* c1  = wsf + 3 * S;
    float* h0b = wsf + 4 * S;
    float* h1b = wsf + 5 * S;
    float* zb  = wsf + 6 * S;
    float* h0buf[2] = {h0a, h0b};
    float* h1buf[2] = {h1a, h1b};

    zero_f_kernel<<<(int)((4 * S + 255) / 256), 256, 0, stream>>>(wsf, (int)(4 * S));

    dim3 grid_lstm(BB / 16, HH / 32);
    for (int t = 0; t < TLEN; ++t) {
        const float* xt = x + (size_t)t * DD;
        gemm_step<0><<<grid_lstm, 256, 0, stream>>>(
            xt, TLEN * DD, DD, W_ih0,
            h0buf[t & 1], HH, W_hh0,
            b_ih0, b_hh0, c0, c0, h0buf[(t + 1) & 1]);
        gemm_step<0><<<grid_lstm, 256, 0, stream>>>(
            h0buf[(t + 1) & 1], HH, HH, W_ih1,
            h1buf[t & 1], HH, W_hh1,
            b_ih1, b_hh1, c1, c1, h1buf[(t + 1) & 1]);
    }
    dim3 grid_fc1(BB / 16, 512 / 128);
    gemm_step<1><<<grid_fc1, 256, 0, stream>>>(
        h1buf[0], HH, HH, W_fc1, nullptr, 0, nullptr,
        b_fc1, nullptr, nullptr, nullptr, zb);
    fc2_kernel<<<BB, 64, 0, stream>>>(zb, W_fc2, b_fc2, out);
}